// Round 9
// baseline (1571.122 us; speedup 1.0000x reference)
//
#include <hip/hip_runtime.h>

#define TT 256
#define BATCH 2048
#define DATA 32
#define WSLOTS 52
#define RPB 4          // batch rows per block -> 512 blocks -> 2 blocks/CU

typedef __bf16 bf16x8 __attribute__((ext_vector_type(8)));
typedef float f32x4 __attribute__((ext_vector_type(4)));

union bfp2 { uint2 u; __bf16 b[4]; };

// fp32 x8 (global) -> bf16x8 fragment (prologue only)
__device__ __forceinline__ bf16x8 ldw8(const float* __restrict__ p) {
    float4 a = *(const float4*)p;
    float4 b = *(const float4*)(p + 4);
    bf16x8 r;
    r[0] = (__bf16)a.x; r[1] = (__bf16)a.y; r[2] = (__bf16)a.z; r[3] = (__bf16)a.w;
    r[4] = (__bf16)b.x; r[5] = (__bf16)b.y; r[6] = (__bf16)b.z; r[7] = (__bf16)b.w;
    return r;
}

// swizzled LDS fragment read: 256-B row stride, 16-B slot XOR (row&7)
__device__ __forceinline__ bf16x8 ldx(const char* base, int row, int kbyte) {
    return *(const bf16x8*)(base + row * 256 + (kbyte ^ ((row & 7) << 4)));
}

// Two 16-col output tiles (this wave's share of a 128-wide layer). R4-exact.
#define HID2(WF, KC, SRC, DST, BI0, BI1)                                              \
    {                                                                                 \
        bf16x8 xf[4];                                                                 \
        _Pragma("unroll") for (int kc = 0; kc < (KC); ++kc)                           \
            xf[kc] = ldx(SRC, m, kc * 64 + g * 16);                                   \
        f32x4 a0 = BI0, a1 = BI1;                                                     \
        _Pragma("unroll") for (int kc = 0; kc < (KC); ++kc) {                         \
            a0 = __builtin_amdgcn_mfma_f32_16x16x32_bf16(WF[0][kc], xf[kc], a0, 0, 0, 0); \
            a1 = __builtin_amdgcn_mfma_f32_16x16x32_bf16(WF[1][kc], xf[kc], a1, 0, 0, 0); \
        }                                                                             \
        bfp2 p0, p1;                                                                  \
        _Pragma("unroll") for (int j = 0; j < 4; ++j) {                               \
            p0.b[j] = (__bf16)fmaxf(a0[j], 0.0f);                                     \
            p1.b[j] = (__bf16)fmaxf(a1[j], 0.0f);                                     \
        }                                                                             \
        char* dr = (DST) + m * 256;                                                   \
        *(uint2*)(dr + ((tbB + g * 8) ^ sw)) = p0.u;                                  \
        *(uint2*)(dr + ((tbB + 32 + g * 8) ^ sw)) = p1.u;                             \
    }

// Assemble x = [y_stage | lerp(hist, tq-1) | lerp(hist, tq-2)] (waves 0/1).
// hist has RPB=4 real rows; junk lanes (m>=4) read aliased rows (m&3) -> finite
// junk confined to their own MFMA columns, never stored to global.
#define ASSEMBLE(USEK, CST, KP)                                                       \
    if (wv < 2) {                                                                     \
        bfp2 py;                                                                      \
        _Pragma("unroll") for (int j = 0; j < 4; ++j)                                 \
            py.b[j] = (__bf16)((USEK) ? fmaf((CST) * dt, KP[j], y[j]) : y[j]);        \
        char* xr = xb + m * 256;                                                      \
        *(uint2*)(xr + (cb2 ^ sw)) = py.u;                                            \
        const float tq = fmaf((CST), dt, t);                                          \
        _Pragma("unroll") for (int dl = 0; dl < 2; ++dl) {                            \
            float s = (tq - (dl ? 2.0f : 1.0f) - t0v) * ivd0;                         \
            s = fminf(fmaxf(s, 0.0f), 255.0f);                                        \
            const int   i0 = (int)s;                                                  \
            const int   i1 = min(i0 + 1, TT - 1);                                     \
            const float w  = s - (float)i0;                                           \
            bfp2 pa, pb, pr;                                                          \
            pa.u = *(const uint2*)(histc + (i0 % WSLOTS) * (RPB * 72) + hrow + cb2);  \
            pb.u = *(const uint2*)(histc + (i1 % WSLOTS) * (RPB * 72) + hrow + cb2);  \
            _Pragma("unroll") for (int j = 0; j < 4; ++j) {                           \
                const float va = (float)pa.b[j];                                      \
                pr.b[j] = (__bf16)fmaf(w, (float)pb.b[j] - va, va);                   \
            }                                                                         \
            *(uint2*)(xr + ((64 + dl * 64 + cb2) ^ sw)) = pr.u;                       \
        }                                                                             \
    }

#define DO_STAGE(USEK, CST, KP, KD)                                                   \
    ASSEMBLE(USEK, CST, KP)                                                           \
    __syncthreads();                                                                  \
    HID2(W0f, 3, xb, hA, bias0[0], bias0[1])                                          \
    __syncthreads();                                                                  \
    HID2(W1f, 4, hA, hB, bias1[0], bias1[1])                                          \
    __syncthreads();                                                                  \
    HID2(W2f, 4, hB, hA, bias2[0], bias2[1])                                          \
    __syncthreads();                                                                  \
    if (wv < 2) {                                                                     \
        bf16x8 xf[4];                                                                 \
        _Pragma("unroll") for (int kc = 0; kc < 4; ++kc)                              \
            xf[kc] = ldx(hA, m, kc * 64 + g * 16);                                    \
        f32x4 a = bias3;                                                              \
        _Pragma("unroll") for (int kc = 0; kc < 4; ++kc)                              \
            a = __builtin_amdgcn_mfma_f32_16x16x32_bf16(W3f[kc], xf[kc], a, 0, 0, 0); \
        KD = a;                                                                       \
    }

__global__ __launch_bounds__(256, 1) void dde_4w(
    const float* __restrict__ ts, const float* __restrict__ y0,
    const float* __restrict__ W0, const float* __restrict__ b0,
    const float* __restrict__ W1, const float* __restrict__ b1,
    const float* __restrict__ W2, const float* __restrict__ b2,
    const float* __restrict__ W3, const float* __restrict__ b3,
    float* __restrict__ out)
{
    __shared__ __align__(16) unsigned short hist[WSLOTS][RPB][36]; // 14976 B
    __shared__ __align__(16) char xb[16 * 256];
    __shared__ __align__(16) char hA[16 * 256];
    __shared__ __align__(16) char hB[16 * 256];
    __shared__ float tsb[TT];
    // ~29 KB LDS -> LDS allows >=5 blocks/CU; grid 512 -> 2 blocks/CU

    const int tid  = threadIdx.x;
    const int lane = tid & 63;
    const int wv   = tid >> 6;        // wave 0..3 -> N-tile pair for hidden layers
    const int m    = lane & 15;       // MFMA row (batch row if m < RPB)
    const int g    = lane >> 4;       // k-group / col-quad
    const int tbB  = wv * 64;         // byte base of this wave's first hidden tile
    const int sw   = (m & 7) << 4;
    const int cb   = wv * 16 + g * 4; // owned output cols (waves 0/1 only)
    const int cb2  = cb * 2;
    const int hrow = (m & (RPB - 1)) * 72;
    const int R0   = blockIdx.x * RPB;
    const bool act = (wv < 2) && (m < RPB);
    char* histc = (char*)hist;

    for (int idx = tid; idx < WSLOTS * RPB * 18; idx += 256) ((unsigned*)hist)[idx] = 0u;
    for (int idx = tid; idx < TT; idx += 256) tsb[idx] = ts[idx];

    // ---- register-resident weight fragments: 26 frags = 104 VGPR ----
    bf16x8 W0f[2][3], W1f[2][4], W2f[2][4], W3f[4];
    #pragma unroll
    for (int ti = 0; ti < 2; ++ti) {
        const int rw = (wv * 2 + ti) * 16 + m;
        #pragma unroll
        for (int kc = 0; kc < 3; ++kc) W0f[ti][kc] = ldw8(W0 + rw * 96 + kc * 32 + g * 8);
        #pragma unroll
        for (int kc = 0; kc < 4; ++kc) W1f[ti][kc] = ldw8(W1 + rw * 128 + kc * 32 + g * 8);
        #pragma unroll
        for (int kc = 0; kc < 4; ++kc) W2f[ti][kc] = ldw8(W2 + rw * 128 + kc * 32 + g * 8);
    }
    {
        const int rw3 = (wv & 1) * 16 + m;     // masked row keeps waves 2/3 in-bounds
        #pragma unroll
        for (int kc = 0; kc < 4; ++kc) W3f[kc] = ldw8(W3 + rw3 * 128 + kc * 32 + g * 8);
    }
    f32x4 bias0[2], bias1[2], bias2[2], bias3;
    #pragma unroll
    for (int ti = 0; ti < 2; ++ti) {
        bias0[ti] = *(const f32x4*)(b0 + (wv * 2 + ti) * 16 + g * 4);
        bias1[ti] = *(const f32x4*)(b1 + (wv * 2 + ti) * 16 + g * 4);
        bias2[ti] = *(const f32x4*)(b2 + (wv * 2 + ti) * 16 + g * 4);
    }
    bias3 = *(const f32x4*)(b3 + (wv & 1) * 16 + g * 4);

    __syncthreads();   // hist zero complete before slot-0 init

    f32x4 y = {0.f, 0.f, 0.f, 0.f}, k1 = y, k2 = y, k3 = y;
    if (act) {
        float4 v = *(const float4*)(y0 + (R0 + m) * DATA + cb);
        y[0] = v.x; y[1] = v.y; y[2] = v.z; y[3] = v.w;
        bfp2 p;
        #pragma unroll
        for (int j = 0; j < 4; ++j) p.b[j] = (__bf16)y[j];
        *(uint2*)(histc + hrow + cb2) = p.u;              // hist slot 0 = y0
        *(float4*)(out + (R0 + m) * DATA + cb) = v;       // ys[0] = y0 exact
    }
    if (blockIdx.x == 0 && tid == 0)
        out[(size_t)TT * BATCH * DATA] = 255.0f;          // tuple output 1: int32(T-1)
    __syncthreads();

    const float t0v  = tsb[0];
    const float ivd0 = 1.0f / (tsb[1] - tsb[0]);

    #pragma unroll 1
    for (int i = 0; i < TT - 1; ++i) {
        const float t  = tsb[i];
        const float dt = tsb[i + 1] - t;

        DO_STAGE(0, 0.0f,  k1, k1)
        DO_STAGE(1, 0.5f,  k1, k2)
        DO_STAGE(2, 0.75f, k2, k3)

        if (wv < 2) {
            #pragma unroll
            for (int j = 0; j < 4; ++j) {
                const float ks = (2.0f / 9.0f) * k1[j] + (1.0f / 3.0f) * k2[j]
                               + (4.0f / 9.0f) * k3[j];
                y[j] = fmaf(dt, ks, y[j]);
            }
            if (m < RPB) {
                bfp2 p; float4 v;
                p.b[0] = (__bf16)y[0]; p.b[1] = (__bf16)y[1];
                p.b[2] = (__bf16)y[2]; p.b[3] = (__bf16)y[3];
                v.x = y[0]; v.y = y[1]; v.z = y[2]; v.w = y[3];
                *(uint2*)(histc + ((i + 1) % WSLOTS) * (RPB * 72) + hrow + cb2) = p.u;
                *(float4*)(out + (size_t)(i + 1) * BATCH * DATA + (R0 + m) * DATA + cb) = v;
            }
        }
        // hist slot (i+1) first read at step >= i+26 (>=75 barriers later);
        // h buffers: >=2 barriers between last read and next write; xb's next
        // writer (ASSEMBLE) is >=1 barrier after its last reader (L0).
    }
}

extern "C" void kernel_launch(void* const* d_in, const int* in_sizes, int n_in,
                              void* d_out, int out_size, void* d_ws, size_t ws_size,
                              hipStream_t stream) {
    const float* ts = (const float*)d_in[0];
    const float* y0 = (const float*)d_in[1];
    const float* W0 = (const float*)d_in[2];
    const float* b0 = (const float*)d_in[3];
    const float* W1 = (const float*)d_in[4];
    const float* b1 = (const float*)d_in[5];
    const float* W2 = (const float*)d_in[6];
    const float* b2 = (const float*)d_in[7];
    const float* W3 = (const float*)d_in[8];
    const float* b3 = (const float*)d_in[9];

    dde_4w<<<dim3(BATCH / RPB), dim3(256), 0, stream>>>(
        ts, y0, W0, b0, W1, b1, W2, b2, W3, b3, (float*)d_out);
}

// Round 10
// 723.665 us; speedup vs baseline: 2.1711x; 2.1711x over previous
//
#include <hip/hip_runtime.h>

#define TT 256
#define BATCH 2048
#define DATA 32
#define WSLOTS 52

typedef __bf16 bf16x8 __attribute__((ext_vector_type(8)));
typedef float f32x4 __attribute__((ext_vector_type(4)));

#define MFMA(A, B, C) __builtin_amdgcn_mfma_f32_16x16x32_bf16((A), (B), (C), 0, 0, 0)

union bfp2 { uint2 u; __bf16 b[4]; };

// fp32 x8 (global) -> bf16x8 fragment (prologue only)
__device__ __forceinline__ bf16x8 ldw8(const float* __restrict__ p) {
    float4 a = *(const float4*)p;
    float4 b = *(const float4*)(p + 4);
    bf16x8 r;
    r[0] = (__bf16)a.x; r[1] = (__bf16)a.y; r[2] = (__bf16)a.z; r[3] = (__bf16)a.w;
    r[4] = (__bf16)b.x; r[5] = (__bf16)b.y; r[6] = (__bf16)b.z; r[7] = (__bf16)b.w;
    return r;
}

// swizzled LDS fragment read: 256-B row stride, 16-B slot XOR (row&7)
__device__ __forceinline__ bf16x8 ldx(const char* base, int row, int kbyte) {
    return *(const bf16x8*)(base + row * 256 + (kbyte ^ ((row & 7) << 4)));
}

// Two 16-col output tiles (R4-exact). A=weight frags (regs), B=activations (LDS).
#define HID2(WF, KC, SRC, DST, BI0, BI1)                                              \
    {                                                                                 \
        bf16x8 xf[4];                                                                 \
        _Pragma("unroll") for (int kc = 0; kc < (KC); ++kc)                           \
            xf[kc] = ldx(SRC, m, kc * 64 + g * 16);                                   \
        f32x4 a0 = BI0, a1 = BI1;                                                     \
        _Pragma("unroll") for (int kc = 0; kc < (KC); ++kc) {                         \
            a0 = MFMA(WF[0][kc], xf[kc], a0);                                         \
            a1 = MFMA(WF[1][kc], xf[kc], a1);                                         \
        }                                                                             \
        bfp2 p0, p1;                                                                  \
        _Pragma("unroll") for (int j = 0; j < 4; ++j) {                               \
            p0.b[j] = (__bf16)fmaxf(a0[j], 0.0f);                                     \
            p1.b[j] = (__bf16)fmaxf(a1[j], 0.0f);                                     \
        }                                                                             \
        char* dr = (DST) + m * 256;                                                   \
        *(uint2*)(dr + ((tbB + g * 8) ^ sw)) = p0.u;                                  \
        *(uint2*)(dr + ((tbB + 32 + g * 8) ^ sw)) = p1.u;                             \
    }

// waves 2/3: compute lerp columns (dl = wv-2) for target time TQT into XDST's
// lerp region (bytes 64..191). Runs in the L3 segment (waves 2/3 idle there).
#define PRELERP(TQT, XDST)                                                            \
    {                                                                                 \
        const int   dl  = wv - 2;                                                     \
        const float tau = dl ? 2.0f : 1.0f;                                           \
        float s = ((TQT) - tau - t0v) * ivd0;                                         \
        s = fminf(fmaxf(s, 0.0f), 255.0f);                                            \
        const int   i0 = (int)s;                                                      \
        const int   i1 = min(i0 + 1, TT - 1);                                         \
        const float w  = s - (float)i0;                                               \
        const char* h0p = histc + (i0 % WSLOTS) * 1152 + m * 72;                      \
        const char* h1p = histc + (i1 % WSLOTS) * 1152 + m * 72;                      \
        char* xr = (XDST) + m * 256;                                                  \
        _Pragma("unroll") for (int q = 0; q < 2; ++q) {                               \
            const int c2 = (q * 16 + g * 4) * 2;                                      \
            bfp2 pa, pb, pr;                                                          \
            pa.u = *(const uint2*)(h0p + c2);                                         \
            pb.u = *(const uint2*)(h1p + c2);                                         \
            _Pragma("unroll") for (int j = 0; j < 4; ++j) {                           \
                const float va = (float)pa.b[j];                                      \
                pr.b[j] = (__bf16)fmaf(w, (float)pb.b[j] - va, va);                   \
            }                                                                         \
            *(uint2*)(xr + ((64 + dl * 64 + c2) ^ sw)) = pr.u;                        \
        }                                                                             \
    }

// One RK stage. XSRC: this stage's x buffer (lerp region pre-filled >=4 barriers
// ago). XDST/TQT: the stage-(s+2) lerp buffer filled by waves 2/3 in the L3 seg.
#define DO_STAGE(USEK, CST, KP, KD, XSRC, XDST, TQT)                                  \
    {                                                                                 \
        /* pre-b1: lerp-part of L0 (all waves), yst write (waves 0/1) */              \
        bf16x8 xl1 = ldx(XSRC, m, 64 + g * 16);                                       \
        bf16x8 xl2 = ldx(XSRC, m, 128 + g * 16);                                      \
        f32x4 p0 = bias0[0], p1 = bias0[1];                                           \
        p0 = MFMA(W0f[0][1], xl1, p0); p1 = MFMA(W0f[1][1], xl1, p1);                 \
        p0 = MFMA(W0f[0][2], xl2, p0); p1 = MFMA(W0f[1][2], xl2, p1);                 \
        if (wv < 2) {                                                                 \
            bfp2 py;                                                                  \
            _Pragma("unroll") for (int j = 0; j < 4; ++j)                             \
                py.b[j] = (__bf16)((USEK) ? fmaf((CST) * dt, KP[j], y[j]) : y[j]);    \
            *(uint2*)((XSRC) + m * 256 + (cb2 ^ sw)) = py.u;                          \
        }                                                                             \
        __syncthreads();                                                              \
        {   /* post-b1: finish L0 with the single y-chunk MFMA */                     \
            bf16x8 xf0 = ldx(XSRC, m, g * 16);                                        \
            p0 = MFMA(W0f[0][0], xf0, p0);                                            \
            p1 = MFMA(W0f[1][0], xf0, p1);                                            \
            bfp2 q0, q1;                                                              \
            _Pragma("unroll") for (int j = 0; j < 4; ++j) {                           \
                q0.b[j] = (__bf16)fmaxf(p0[j], 0.0f);                                 \
                q1.b[j] = (__bf16)fmaxf(p1[j], 0.0f);                                 \
            }                                                                         \
            char* dr = hA + m * 256;                                                  \
            *(uint2*)(dr + ((tbB + g * 8) ^ sw)) = q0.u;                              \
            *(uint2*)(dr + ((tbB + 32 + g * 8) ^ sw)) = q1.u;                         \
        }                                                                             \
        __syncthreads();                                                              \
        HID2(W1f, 4, hA, hB, bias1[0], bias1[1])                                      \
        __syncthreads();                                                              \
        HID2(W2f, 4, hB, hA, bias2[0], bias2[1])                                      \
        __syncthreads();                                                              \
        if (wv < 2) {                                                                 \
            bf16x8 xf[4];                                                             \
            _Pragma("unroll") for (int kc = 0; kc < 4; ++kc)                          \
                xf[kc] = ldx(hA, m, kc * 64 + g * 16);                                \
            f32x4 a = bias3;                                                          \
            _Pragma("unroll") for (int kc = 0; kc < 4; ++kc)                          \
                a = MFMA(W3f[kc], xf[kc], a);                                         \
            KD = a;                                                                   \
        } else {                                                                      \
            PRELERP(TQT, XDST)                                                        \
        }                                                                             \
    }

__global__ __launch_bounds__(256, 1) void dde_pl(
    const float* __restrict__ ts, const float* __restrict__ y0,
    const float* __restrict__ W0, const float* __restrict__ b0,
    const float* __restrict__ W1, const float* __restrict__ b1,
    const float* __restrict__ W2, const float* __restrict__ b2,
    const float* __restrict__ W3, const float* __restrict__ b3,
    float* __restrict__ out)
{
    __shared__ __align__(16) unsigned short hist[WSLOTS][16][36]; // 59904 B
    __shared__ __align__(16) char xb0[16 * 256];   // per-stage x buffers
    __shared__ __align__(16) char xb1[16 * 256];
    __shared__ __align__(16) char xb2[16 * 256];
    __shared__ __align__(16) char hA[16 * 256];
    __shared__ __align__(16) char hB[16 * 256];
    __shared__ float tsb[TT];
    // ~81 KB LDS

    const int tid  = threadIdx.x;
    const int lane = tid & 63;
    const int wv   = tid >> 6;        // wave 0..3
    const int m    = lane & 15;       // batch row within block
    const int g    = lane >> 4;
    const int tbB  = wv * 64;
    const int sw   = (m & 7) << 4;
    const int cb   = wv * 16 + g * 4; // owned output cols (waves 0/1 only)
    const int cb2  = cb * 2;
    const int R0   = blockIdx.x * 16;
    char* histc = (char*)hist;

    for (int idx = tid; idx < WSLOTS * 16 * 18; idx += 256) ((unsigned*)hist)[idx] = 0u;
    for (int idx = tid; idx < TT; idx += 256) tsb[idx] = ts[idx];

    // ---- register-resident weight fragments (R4-identical) ----
    bf16x8 W0f[2][3], W1f[2][4], W2f[2][4], W3f[4];
    #pragma unroll
    for (int ti = 0; ti < 2; ++ti) {
        const int rw = (wv * 2 + ti) * 16 + m;
        #pragma unroll
        for (int kc = 0; kc < 3; ++kc) W0f[ti][kc] = ldw8(W0 + rw * 96 + kc * 32 + g * 8);
        #pragma unroll
        for (int kc = 0; kc < 4; ++kc) W1f[ti][kc] = ldw8(W1 + rw * 128 + kc * 32 + g * 8);
        #pragma unroll
        for (int kc = 0; kc < 4; ++kc) W2f[ti][kc] = ldw8(W2 + rw * 128 + kc * 32 + g * 8);
    }
    {
        const int rw3 = (wv & 1) * 16 + m;
        #pragma unroll
        for (int kc = 0; kc < 4; ++kc) W3f[kc] = ldw8(W3 + rw3 * 128 + kc * 32 + g * 8);
    }
    f32x4 bias0[2], bias1[2], bias2[2], bias3;
    #pragma unroll
    for (int ti = 0; ti < 2; ++ti) {
        bias0[ti] = *(const f32x4*)(b0 + (wv * 2 + ti) * 16 + g * 4);
        bias1[ti] = *(const f32x4*)(b1 + (wv * 2 + ti) * 16 + g * 4);
        bias2[ti] = *(const f32x4*)(b2 + (wv * 2 + ti) * 16 + g * 4);
    }
    bias3 = *(const f32x4*)(b3 + (wv & 1) * 16 + g * 4);

    __syncthreads();   // hist zero complete

    f32x4 y = {0.f, 0.f, 0.f, 0.f}, k1 = y, k2 = y, k3 = y;
    if (wv < 2) {
        float4 v = *(const float4*)(y0 + (R0 + m) * DATA + cb);
        y[0] = v.x; y[1] = v.y; y[2] = v.z; y[3] = v.w;
        bfp2 p;
        #pragma unroll
        for (int j = 0; j < 4; ++j) p.b[j] = (__bf16)y[j];
        *(uint2*)(histc + m * 72 + cb2) = p.u;            // hist slot 0 = y0
        *(float4*)(out + (R0 + m) * DATA + cb) = v;       // ys[0] = y0 exact
    }
    if (blockIdx.x == 0 && tid == 0)
        out[(size_t)TT * BATCH * DATA] = 255.0f;          // tuple output 1: int32(T-1)
    __syncthreads();   // hist slot 0 visible

    const float t0v  = tsb[0];
    const float ivd0 = 1.0f / (tsb[1] - tsb[0]);

    // ---- prologue: fill all three stage lerp buffers for step 0 ----
    if (wv >= 2) {
        const float dt0 = tsb[1] - tsb[0];
        PRELERP(t0v, xb0)
        PRELERP(fmaf(0.5f, dt0, t0v), xb1)
        PRELERP(fmaf(0.75f, dt0, t0v), xb2)
    }
    __syncthreads();   // lerp buffers visible

    #pragma unroll 1
    for (int i = 0; i < TT - 1; ++i) {
        const float t   = tsb[i];
        const float tn  = tsb[i + 1];
        const float dt  = tn - t;
        const float tnn = tsb[min(i + 2, TT - 1)];
        const float dtn = tnn - tn;          // 0 on the final iteration (unused junk)

        DO_STAGE(0, 0.0f,  k1, k1, xb0, xb2, fmaf(0.75f, dt, t))
        DO_STAGE(1, 0.5f,  k1, k2, xb1, xb0, tn)
        DO_STAGE(2, 0.75f, k2, k3, xb2, xb1, fmaf(0.5f, dtn, tn))

        if (wv < 2) {
            #pragma unroll
            for (int j = 0; j < 4; ++j) {
                const float ks = (2.0f / 9.0f) * k1[j] + (1.0f / 3.0f) * k2[j]
                               + (4.0f / 9.0f) * k3[j];
                y[j] = fmaf(dt, ks, y[j]);
            }
            bfp2 p; float4 v;
            p.b[0] = (__bf16)y[0]; p.b[1] = (__bf16)y[1];
            p.b[2] = (__bf16)y[2]; p.b[3] = (__bf16)y[3];
            v.x = y[0]; v.y = y[1]; v.z = y[2]; v.w = y[3];
            *(uint2*)(histc + ((i + 1) % WSLOTS) * 1152 + m * 72 + cb2) = p.u;
            *(float4*)(out + (size_t)(i + 1) * BATCH * DATA + (R0 + m) * DATA + cb) = v;
        }
        // Hazards: xb lerp regions written in L3 seg of stage s, read pre-b1 of
        // stage s+2 (>=4 barriers). WAR on same buffer >=8 barriers. hist write
        // (slot i+1) vs PRELERP reads (slots <= i-24) disjoint; first read of
        // slot i+1 is >=25 steps later. hA/hB: R4-proven 2-buffer rotation.
    }
}

extern "C" void kernel_launch(void* const* d_in, const int* in_sizes, int n_in,
                              void* d_out, int out_size, void* d_ws, size_t ws_size,
                              hipStream_t stream) {
    const float* ts = (const float*)d_in[0];
    const float* y0 = (const float*)d_in[1];
    const float* W0 = (const float*)d_in[2];
    const float* b0 = (const float*)d_in[3];
    const float* W1 = (const float*)d_in[4];
    const float* b1 = (const float*)d_in[5];
    const float* W2 = (const float*)d_in[6];
    const float* b2 = (const float*)d_in[7];
    const float* W3 = (const float*)d_in[8];
    const float* b3 = (const float*)d_in[9];

    dde_pl<<<dim3(BATCH / 16), dim3(256), 0, stream>>>(
        ts, y0, W0, b0, W1, b1, W2, b2, W3, b3, (float*)d_out);
}